// Round 1
// baseline (1563.318 us; speedup 1.0000x reference)
//
#include <hip/hip_runtime.h>
#include <cstdint>
#include <cstddef>

#define NB 32      // batch
#define NT 2000    // timesteps
#define NI 256     // input dim
#define NN 512     // neurons
#define M_TOT (NB * NT)   // 64000 rows of the input GEMM

// ---------------- transpose R -> Rt (Rt[j][n] = R[n][j]) ----------------
__global__ void transpose_R(const float* __restrict__ R, float* __restrict__ Rt) {
    int idx = blockIdx.x * blockDim.x + threadIdx.x;
    if (idx >= NN * NN) return;
    int j = idx >> 9;          // Rt row
    int n = idx & (NN - 1);    // Rt col (coalesced write)
    Rt[idx] = R[n * NN + j];
}

// ---------------- GEMM: cur[m][n] = sum_k x[m][k]*W[n][k] + bias[n] ----------------
#define BM 64
#define BN 64
#define BK 32
__global__ __launch_bounds__(256) void gemm_xw(const float* __restrict__ A,
                                               const float* __restrict__ Wt,
                                               const float* __restrict__ bias,
                                               float* __restrict__ C) {
    __shared__ float As[BK][BM];
    __shared__ float Bs[BK][BN];
    const int tid = threadIdx.x;
    const int bm = blockIdx.x * BM;
    const int bn = blockIdx.y * BN;
    const int tx = tid & 15, ty = tid >> 4;
    const int lrow = tid >> 2;          // 0..63
    const int lk = (tid & 3) * 8;       // 0,8,16,24
    float acc[4][4] = {};
    const float* Arow = A + (size_t)(bm + lrow) * NI + lk;
    const float* Brow = Wt + (size_t)(bn + lrow) * NI + lk;
    for (int k0 = 0; k0 < NI; k0 += BK) {
        float4 a0 = *(const float4*)(Arow + k0);
        float4 a1 = *(const float4*)(Arow + k0 + 4);
        float4 b0 = *(const float4*)(Brow + k0);
        float4 b1 = *(const float4*)(Brow + k0 + 4);
        __syncthreads();
        As[lk + 0][lrow] = a0.x; As[lk + 1][lrow] = a0.y;
        As[lk + 2][lrow] = a0.z; As[lk + 3][lrow] = a0.w;
        As[lk + 4][lrow] = a1.x; As[lk + 5][lrow] = a1.y;
        As[lk + 6][lrow] = a1.z; As[lk + 7][lrow] = a1.w;
        Bs[lk + 0][lrow] = b0.x; Bs[lk + 1][lrow] = b0.y;
        Bs[lk + 2][lrow] = b0.z; Bs[lk + 3][lrow] = b0.w;
        Bs[lk + 4][lrow] = b1.x; Bs[lk + 5][lrow] = b1.y;
        Bs[lk + 6][lrow] = b1.z; Bs[lk + 7][lrow] = b1.w;
        __syncthreads();
        #pragma unroll
        for (int k = 0; k < BK; ++k) {
            float4 av = *(const float4*)&As[k][ty * 4];
            float4 bv = *(const float4*)&Bs[k][tx * 4];
            acc[0][0] += av.x * bv.x; acc[0][1] += av.x * bv.y;
            acc[0][2] += av.x * bv.z; acc[0][3] += av.x * bv.w;
            acc[1][0] += av.y * bv.x; acc[1][1] += av.y * bv.y;
            acc[1][2] += av.y * bv.z; acc[1][3] += av.y * bv.w;
            acc[2][0] += av.z * bv.x; acc[2][1] += av.z * bv.y;
            acc[2][2] += av.z * bv.z; acc[2][3] += av.z * bv.w;
            acc[3][0] += av.w * bv.x; acc[3][1] += av.w * bv.y;
            acc[3][2] += av.w * bv.z; acc[3][3] += av.w * bv.w;
        }
    }
    #pragma unroll
    for (int i = 0; i < 4; ++i) {
        const int row = bm + ty * 4 + i;
        #pragma unroll
        for (int j = 0; j < 4; ++j) {
            const int col = bn + tx * 4 + j;
            C[(size_t)row * NN + col] = acc[i][j] + bias[col];
        }
    }
}

// ---------------- sequential LIF scan, one block per batch element ----------------
// State update mirrors numpy's exact op order (no FMA contraction) so borderline
// spike decisions match the reference within dot-product accumulation noise.
template<bool TRANS>
__global__ __launch_bounds__(512) void scan_lif(const float* __restrict__ cur,
        const float* __restrict__ Rm,   // Rt (TRANS) or R (fallback)
        const float* __restrict__ du_g, const float* __restrict__ dw_g,
        const float* __restrict__ a_g, const float* __restrict__ b_g,
        float* __restrict__ out) {
    __shared__ unsigned long long masks[2][8];   // double-buffered spike bitmask
    const int n = threadIdx.x;
    const int b = blockIdx.x;
    const int wave = n >> 6;
    const float du = du_g[n], dw = dw_g[n];
    const float an = a_g[n], bn = b_g[n];
    const float odu = 1.0f - du, odw = 1.0f - dw;
    float u = 0.0f, w = 0.0f, z = 0.0f;
    if (n < 8) masks[0][n] = 0ULL;
    __syncthreads();
    const float* curb = cur + (size_t)b * NT * NN + n;
    float* outb = out + (size_t)b * NT * NN + n;
    float cpre = curb[0];                      // prefetch t=0
    for (int t = 0; t < NT; ++t) {
        float c_in = cpre;
        if (t + 1 < NT) cpre = curb[(size_t)(t + 1) * NN];   // prefetch next step
        // sparse recurrent input: sum active columns of R^T (uniform across lanes)
        float rec = 0.0f;
        #pragma unroll
        for (int wi = 0; wi < 8; ++wi) {
            unsigned long long m = masks[t & 1][wi];
            while (m) {
                int bit = __builtin_ctzll(m);
                m &= m - 1;
                int j = (wi << 6) + bit;
                rec += TRANS ? Rm[(size_t)j * NN + n] : Rm[(size_t)n * NN + j];
            }
        }
        float c = __fadd_rn(c_in, rec);
        // u = du*u_prev + (1-du)*(c - w_prev)
        float unew = __fadd_rn(__fmul_rn(du, u), __fmul_rn(odu, __fsub_rn(c, w)));
        float zn = (__fsub_rn(unew, 1.0f) > 0.0f) ? 1.0f : 0.0f;
        // w = dw*w_prev + ((1-dw)*(a*u_prev + b*z_prev))*Q   (uses pre-update u,z)
        float s = __fadd_rn(__fmul_rn(an, u), __fmul_rn(bn, z));
        float wnew = __fadd_rn(__fmul_rn(dw, w), __fmul_rn(__fmul_rn(odw, s), 120.0f));
        u = __fmul_rn(unew, __fsub_rn(1.0f, zn));   // reset
        w = wnew;
        z = zn;
        outb[(size_t)t * NN] = zn;
        // publish z_t bitmask for next step (other buffer; one barrier/step)
        unsigned long long bal = __ballot(zn > 0.0f);
        if ((n & 63) == 0) masks[(t + 1) & 1][wave] = bal;
        __syncthreads();
    }
}

extern "C" void kernel_launch(void* const* d_in, const int* in_sizes, int n_in,
                              void* d_out, int out_size, void* d_ws, size_t ws_size,
                              hipStream_t stream) {
    const float* x    = (const float*)d_in[0];   // [B,T,I]
    const float* W    = (const float*)d_in[1];   // [N,I]
    const float* bias = (const float*)d_in[2];   // [N]
    const float* R    = (const float*)d_in[3];   // [N,N]
    const float* du   = (const float*)d_in[4];
    const float* dw   = (const float*)d_in[5];
    const float* a    = (const float*)d_in[6];
    const float* b    = (const float*)d_in[7];
    float* out = (float*)d_out;                  // [B,T,N] fp32 spikes

    const size_t curBytes = (size_t)M_TOT * NN * sizeof(float);   // 131 MB
    const size_t rtBytes  = (size_t)NN * NN * sizeof(float);      // 1 MB
    float* Rt  = nullptr;
    float* cur;
    if (ws_size >= rtBytes + curBytes) {
        Rt  = (float*)d_ws;
        cur = (float*)d_ws + (size_t)NN * NN;
    } else if (ws_size >= rtBytes) {
        Rt  = (float*)d_ws;
        cur = out;          // read-before-overwrite per element is safe
    } else {
        cur = out;
    }

    if (Rt) {
        transpose_R<<<(NN * NN + 255) / 256, 256, 0, stream>>>(R, Rt);
    }
    dim3 ggrid(M_TOT / BM, NN / BN);
    gemm_xw<<<ggrid, 256, 0, stream>>>(x, W, bias, cur);
    if (Rt) {
        scan_lif<true><<<NB, NN, 0, stream>>>(cur, Rt, du, dw, a, b, out);
    } else {
        scan_lif<false><<<NB, NN, 0, stream>>>(cur, R, du, dw, a, b, out);
    }
}

// Round 6
// 1232.681 us; speedup vs baseline: 1.2682x; 1.2682x over previous
//
#include <hip/hip_runtime.h>
#include <cstdint>
#include <cstddef>

#define NB 32      // batch
#define NT 2000    // timesteps
#define NI 256     // input dim
#define NN 512     // neurons
#define M_TOT (NB * NT)   // 64000 rows of the input GEMM

// ---------------- transpose R -> Rt (Rt[j][n] = R[n][j]) ----------------
__global__ void transpose_R(const float* __restrict__ R, float* __restrict__ Rt) {
    int idx = blockIdx.x * blockDim.x + threadIdx.x;
    if (idx >= NN * NN) return;
    int j = idx >> 9;          // Rt row
    int n = idx & (NN - 1);    // Rt col (coalesced write)
    Rt[idx] = R[n * NN + j];
}

// ---------------- GEMM: cur[m][n] = sum_k x[m][k]*W[n][k] + bias[n] ----------------
// 128x128 tile, BK=16, 256 threads, 8x8 per thread. k strictly ascending per
// accumulator (same summation-order class as the round-1 passing kernel).
#define GBM 128
#define GBN 128
#define GBK 16
__global__ __launch_bounds__(256) void gemm_xw(const float* __restrict__ A,
                                               const float* __restrict__ Wt,
                                               const float* __restrict__ bias,
                                               float* __restrict__ C) {
    __shared__ float As[GBK][GBM];
    __shared__ float Bs[GBK][GBN];
    const int tid = threadIdx.x;
    const int bm = blockIdx.x * GBM;
    const int bn = blockIdx.y * GBN;
    const int tx = tid & 15, ty = tid >> 4;      // 16x16 thread grid
    const int lrow = tid >> 1;                   // 0..127
    const int lk = (tid & 1) * 8;                // 0 or 8
    float acc[8][8] = {};
    const float* Arow = A + (size_t)(bm + lrow) * NI + lk;
    const float* Brow = Wt + (size_t)(bn + lrow) * NI + lk;
    for (int k0 = 0; k0 < NI; k0 += GBK) {
        float4 a0 = *(const float4*)(Arow + k0);
        float4 a1 = *(const float4*)(Arow + k0 + 4);
        float4 b0 = *(const float4*)(Brow + k0);
        float4 b1 = *(const float4*)(Brow + k0 + 4);
        __syncthreads();
        As[lk + 0][lrow] = a0.x; As[lk + 1][lrow] = a0.y;
        As[lk + 2][lrow] = a0.z; As[lk + 3][lrow] = a0.w;
        As[lk + 4][lrow] = a1.x; As[lk + 5][lrow] = a1.y;
        As[lk + 6][lrow] = a1.z; As[lk + 7][lrow] = a1.w;
        Bs[lk + 0][lrow] = b0.x; Bs[lk + 1][lrow] = b0.y;
        Bs[lk + 2][lrow] = b0.z; Bs[lk + 3][lrow] = b0.w;
        Bs[lk + 4][lrow] = b1.x; Bs[lk + 5][lrow] = b1.y;
        Bs[lk + 6][lrow] = b1.z; Bs[lk + 7][lrow] = b1.w;
        __syncthreads();
        #pragma unroll
        for (int k = 0; k < GBK; ++k) {
            float4 av0 = *(const float4*)&As[k][ty * 8];
            float4 av1 = *(const float4*)&As[k][ty * 8 + 4];
            float4 bv0 = *(const float4*)&Bs[k][tx * 8];
            float4 bv1 = *(const float4*)&Bs[k][tx * 8 + 4];
            float a_[8] = {av0.x, av0.y, av0.z, av0.w, av1.x, av1.y, av1.z, av1.w};
            float b_[8] = {bv0.x, bv0.y, bv0.z, bv0.w, bv1.x, bv1.y, bv1.z, bv1.w};
            #pragma unroll
            for (int i = 0; i < 8; ++i)
                #pragma unroll
                for (int j = 0; j < 8; ++j)
                    acc[i][j] += a_[i] * b_[j];
        }
    }
    #pragma unroll
    for (int i = 0; i < 8; ++i) {
        const int row = bm + ty * 8 + i;
        #pragma unroll
        for (int j = 0; j < 8; ++j) {
            const int col = bn + tx * 8 + j;
            C[(size_t)row * NN + col] = acc[i][j] + bias[col];
        }
    }
}

// ---------------- wave-synchronous LIF scan: 1 wave per batch element ----------------
// 64 lanes x 8 contiguous neurons/lane. Spike masks in registers via __ballot:
// no LDS, no __syncthreads. Recurrent gather = 2 coalesced float4 loads per
// spiking neuron. State math mirrors numpy's exact op order (no contraction).

#define UPD(C_, R_, DU_, ODU_, DW_, ODW_, A_, B_, U_, W_, Z_) do {               \
    float cc_   = __fadd_rn((C_), (R_));                                         \
    float unew_ = __fadd_rn(__fmul_rn((DU_), (U_)),                              \
                            __fmul_rn((ODU_), __fsub_rn(cc_, (W_))));            \
    float zn_   = (__fsub_rn(unew_, 1.0f) > 0.0f) ? 1.0f : 0.0f;                 \
    float s_    = __fadd_rn(__fmul_rn((A_), (U_)), __fmul_rn((B_), (Z_)));       \
    float wnew_ = __fadd_rn(__fmul_rn((DW_), (W_)),                              \
                            __fmul_rn(__fmul_rn((ODW_), s_), 120.0f));           \
    (U_) = __fmul_rn(unew_, __fsub_rn(1.0f, zn_));                               \
    (W_) = wnew_;                                                                \
    (Z_) = zn_;                                                                  \
} while (0)

template<bool TRANS>
__global__ __launch_bounds__(64) void scan_wave(const float* __restrict__ cur,
        const float* __restrict__ Rm,   // Rt (TRANS) or R (fallback)
        const float* __restrict__ du_g, const float* __restrict__ dw_g,
        const float* __restrict__ a_g, const float* __restrict__ b_g,
        float* __restrict__ out) {
    const int lane = threadIdx.x & 63;
    const int b = blockIdx.x;
    const int n0 = lane << 3;            // 8 contiguous neurons per lane

    const float4 du0 = *(const float4*)(du_g + n0);
    const float4 du1 = *(const float4*)(du_g + n0 + 4);
    const float4 dw0 = *(const float4*)(dw_g + n0);
    const float4 dw1 = *(const float4*)(dw_g + n0 + 4);
    const float4 an0 = *(const float4*)(a_g + n0);
    const float4 an1 = *(const float4*)(a_g + n0 + 4);
    const float4 bn0 = *(const float4*)(b_g + n0);
    const float4 bn1 = *(const float4*)(b_g + n0 + 4);
    const float4 odu0 = {1.0f - du0.x, 1.0f - du0.y, 1.0f - du0.z, 1.0f - du0.w};
    const float4 odu1 = {1.0f - du1.x, 1.0f - du1.y, 1.0f - du1.z, 1.0f - du1.w};
    const float4 odw0 = {1.0f - dw0.x, 1.0f - dw0.y, 1.0f - dw0.z, 1.0f - dw0.w};
    const float4 odw1 = {1.0f - dw1.x, 1.0f - dw1.y, 1.0f - dw1.z, 1.0f - dw1.w};

    float4 u0 = {0,0,0,0}, u1 = {0,0,0,0};
    float4 w0 = {0,0,0,0}, w1 = {0,0,0,0};
    float4 z0 = {0,0,0,0}, z1 = {0,0,0,0};
    unsigned long long m0=0,m1=0,m2=0,m3=0,m4=0,m5=0,m6=0,m7=0;

    const float* curp = cur + (size_t)b * NT * NN + n0;
    float* outp = out + (size_t)b * NT * NN + n0;
    float4 p0 = *(const float4*)(curp);
    float4 p1 = *(const float4*)(curp + 4);

    for (int t = 0; t < NT; ++t) {
        float4 c0 = p0, c1 = p1;
        if (t + 1 < NT) {                      // prefetch next step's current
            p0 = *(const float4*)(curp + NN);
            p1 = *(const float4*)(curp + NN + 4);
        }
        curp += NN;

        // sparse recurrent input from z_{t-1} masks (wave-uniform, no divergence)
        float4 r0 = {0,0,0,0}, r1 = {0,0,0,0};
        if (m0 | m1 | m2 | m3 | m4 | m5 | m6 | m7) {
            #define GATHER(MM, E) do {                                            \
                unsigned long long g_ = (MM);                                     \
                while (g_) {                                                      \
                    int l_ = __builtin_ctzll(g_); g_ &= g_ - 1;                   \
                    int j_ = (l_ << 3) + (E);                                     \
                    const float* rp_ = TRANS ? (Rm + ((size_t)j_ << 9) + n0)      \
                                             : (Rm + ((size_t)j_));               \
                    float4 q0_, q1_;                                              \
                    if (TRANS) {                                                  \
                        q0_ = *(const float4*)rp_;                                \
                        q1_ = *(const float4*)(rp_ + 4);                          \
                    } else {                                                      \
                        q0_.x = Rm[(size_t)(n0+0)*NN + j_];                       \
                        q0_.y = Rm[(size_t)(n0+1)*NN + j_];                       \
                        q0_.z = Rm[(size_t)(n0+2)*NN + j_];                       \
                        q0_.w = Rm[(size_t)(n0+3)*NN + j_];                       \
                        q1_.x = Rm[(size_t)(n0+4)*NN + j_];                       \
                        q1_.y = Rm[(size_t)(n0+5)*NN + j_];                       \
                        q1_.z = Rm[(size_t)(n0+6)*NN + j_];                       \
                        q1_.w = Rm[(size_t)(n0+7)*NN + j_];                       \
                    }                                                             \
                    r0.x = __fadd_rn(r0.x, q0_.x); r0.y = __fadd_rn(r0.y, q0_.y); \
                    r0.z = __fadd_rn(r0.z, q0_.z); r0.w = __fadd_rn(r0.w, q0_.w); \
                    r1.x = __fadd_rn(r1.x, q1_.x); r1.y = __fadd_rn(r1.y, q1_.y); \
                    r1.z = __fadd_rn(r1.z, q1_.z); r1.w = __fadd_rn(r1.w, q1_.w); \
                }                                                                 \
            } while (0)
            GATHER(m0, 0); GATHER(m1, 1); GATHER(m2, 2); GATHER(m3, 3);
            GATHER(m4, 4); GATHER(m5, 5); GATHER(m6, 6); GATHER(m7, 7);
            #undef GATHER
        }

        UPD(c0.x, r0.x, du0.x, odu0.x, dw0.x, odw0.x, an0.x, bn0.x, u0.x, w0.x, z0.x);
        UPD(c0.y, r0.y, du0.y, odu0.y, dw0.y, odw0.y, an0.y, bn0.y, u0.y, w0.y, z0.y);
        UPD(c0.z, r0.z, du0.z, odu0.z, dw0.z, odw0.z, an0.z, bn0.z, u0.z, w0.z, z0.z);
        UPD(c0.w, r0.w, du0.w, odu0.w, dw0.w, odw0.w, an0.w, bn0.w, u0.w, w0.w, z0.w);
        UPD(c1.x, r1.x, du1.x, odu1.x, dw1.x, odw1.x, an1.x, bn1.x, u1.x, w1.x, z1.x);
        UPD(c1.y, r1.y, du1.y, odu1.y, dw1.y, odw1.y, an1.y, bn1.y, u1.y, w1.y, z1.y);
        UPD(c1.z, r1.z, du1.z, odu1.z, dw1.z, odw1.z, an1.z, bn1.z, u1.z, w1.z, z1.z);
        UPD(c1.w, r1.w, du1.w, odu1.w, dw1.w, odw1.w, an1.w, bn1.w, u1.w, w1.w, z1.w);

        // publish z_t as register bitmasks: m_e bit l <-> neuron l*8+e
        m0 = __ballot(z0.x > 0.5f);
        m1 = __ballot(z0.y > 0.5f);
        m2 = __ballot(z0.z > 0.5f);
        m3 = __ballot(z0.w > 0.5f);
        m4 = __ballot(z1.x > 0.5f);
        m5 = __ballot(z1.y > 0.5f);
        m6 = __ballot(z1.z > 0.5f);
        m7 = __ballot(z1.w > 0.5f);

        *(float4*)outp = z0;
        *(float4*)(outp + 4) = z1;
        outp += NN;
    }
}

extern "C" void kernel_launch(void* const* d_in, const int* in_sizes, int n_in,
                              void* d_out, int out_size, void* d_ws, size_t ws_size,
                              hipStream_t stream) {
    const float* x    = (const float*)d_in[0];   // [B,T,I]
    const float* W    = (const float*)d_in[1];   // [N,I]
    const float* bias = (const float*)d_in[2];   // [N]
    const float* R    = (const float*)d_in[3];   // [N,N]
    const float* du   = (const float*)d_in[4];
    const float* dw   = (const float*)d_in[5];
    const float* a    = (const float*)d_in[6];
    const float* b    = (const float*)d_in[7];
    float* out = (float*)d_out;                  // [B,T,N] fp32 spikes

    const size_t curBytes = (size_t)M_TOT * NN * sizeof(float);   // 131 MB
    const size_t rtBytes  = (size_t)NN * NN * sizeof(float);      // 1 MB
    float* Rt  = nullptr;
    float* cur;
    if (ws_size >= rtBytes + curBytes) {
        Rt  = (float*)d_ws;
        cur = (float*)d_ws + (size_t)NN * NN;
    } else if (ws_size >= rtBytes) {
        Rt  = (float*)d_ws;
        cur = out;          // read-before-overwrite per element is safe
    } else {
        cur = out;
    }

    if (Rt) {
        transpose_R<<<(NN * NN + 255) / 256, 256, 0, stream>>>(R, Rt);
    }
    dim3 ggrid(M_TOT / GBM, NN / GBN);
    gemm_xw<<<ggrid, 256, 0, stream>>>(x, W, bias, cur);
    if (Rt) {
        scan_wave<true><<<NB, 64, 0, stream>>>(cur, Rt, du, dw, a, b, out);
    } else {
        scan_wave<false><<<NB, 64, 0, stream>>>(cur, R, du, dw, a, b, out);
    }
}